// Round 1
// baseline (479.377 us; speedup 1.0000x reference)
//
#include <hip/hip_runtime.h>
#include <hip/hip_bf16.h>
#include <math.h>

// Problem constants
static constexpr int BB = 4;     // batch
static constexpr int CC = 256;   // channels
static constexpr int NN = 4096;  // pixels (64*64)

using bf16   = __bf16;
using bf16x8 = __attribute__((ext_vector_type(8))) __bf16;
using bf16x4 = __attribute__((ext_vector_type(4))) __bf16;
using f32x4  = __attribute__((ext_vector_type(4))) float;

// ---------------------------------------------------------------------------
// fp32 -> bf16 elementwise convert (n multiple of 4)
// ---------------------------------------------------------------------------
__global__ __launch_bounds__(256) void cvt_f32_bf16_kernel(
    const float* __restrict__ in, bf16* __restrict__ out, long n) {
  long i = ((long)blockIdx.x * blockDim.x + threadIdx.x) * 4;
  if (i >= n) return;
  float4 v = *(const float4*)(in + i);
  bf16x4 t;
  t[0] = (bf16)v.x; t[1] = (bf16)v.y; t[2] = (bf16)v.z; t[3] = (bf16)v.w;
  *(bf16x4*)(out + i) = t;
}

// ---------------------------------------------------------------------------
// transpose x [B][C][N] fp32 -> xt [B][N][C] bf16
// ---------------------------------------------------------------------------
__global__ __launch_bounds__(256) void transpose_x_kernel(
    const float* __restrict__ x, bf16* __restrict__ xt) {
  __shared__ float tile[64][65];
  int b  = blockIdx.z;
  int c0 = blockIdx.x * 64;   // C/64 = 4
  int n0 = blockIdx.y * 64;   // N/64 = 64
  const float* xp = x  + (long)b * CC * NN;
  bf16*       xtp = xt + (long)b * NN * CC;
  int tj = threadIdx.x & 63;
  int ti = threadIdx.x >> 6;
#pragma unroll
  for (int p = 0; p < 16; ++p) {
    int i = ti + p * 4;
    tile[i][tj] = xp[(long)(c0 + i) * NN + n0 + tj];
  }
  __syncthreads();
#pragma unroll
  for (int p = 0; p < 16; ++p) {
    int i = ti + p * 4;  // n offset
    xtp[(long)(n0 + i) * CC + c0 + tj] = (bf16)tile[tj][i];
  }
}

// ---------------------------------------------------------------------------
// Generic NT GEMM: D[r][c] = sum_k A[r][k] * B[c][k]   (both row-major, K contig)
// 256 threads = 4 waves (2x2), block tile 128x128, wave tile 64x64 (4x4 frags)
// BIAS_MODE: 0 none, 1 bias[col], 2 bias[row]
// B_F32: B operand is fp32 in memory, convert to bf16 on load
// GATE_EPI: multiply by (1 + sigmoid(ge_flat[row*4096 + col])) per batch
// ---------------------------------------------------------------------------
template <int BIAS_MODE, bool B_F32, bool OUT_BF16, bool GATE_EPI>
__global__ __launch_bounds__(256) void gemm_nt_kernel(
    const bf16* __restrict__ A, const void* __restrict__ Bm,
    const float* __restrict__ bias, void* __restrict__ D,
    const float* __restrict__ gefl,
    int M, int NC, int K,
    long sA, long sB, long sD, long sGe) {
  int b = blockIdx.z;
  const bf16*  Ab  = A + b * sA;
  const float* geb = GATE_EPI ? (gefl + b * sGe) : nullptr;

  int wid = threadIdx.x >> 6;
  int l   = threadIdx.x & 63;
  int lr  = l & 15;            // fragment row (A row / B row=output col)
  int lk  = (l >> 4) * 8;      // fragment k offset
  int row0 = blockIdx.y * 128 + (wid >> 1) * 64;
  int col0 = blockIdx.x * 128 + (wid & 1) * 64;

  f32x4 acc[4][4];
#pragma unroll
  for (int i = 0; i < 4; ++i)
#pragma unroll
    for (int j = 0; j < 4; ++j) acc[i][j] = {0.f, 0.f, 0.f, 0.f};

  for (int k0 = 0; k0 < K; k0 += 32) {
    bf16x8 a[4], bb[4];
#pragma unroll
    for (int i = 0; i < 4; ++i)
      a[i] = *(const bf16x8*)(Ab + (long)(row0 + 16 * i + lr) * K + k0 + lk);
    if constexpr (!B_F32) {
      const bf16* Bb = (const bf16*)Bm + b * sB;
#pragma unroll
      for (int j = 0; j < 4; ++j)
        bb[j] = *(const bf16x8*)(Bb + (long)(col0 + 16 * j + lr) * K + k0 + lk);
    } else {
      const float* Bf = (const float*)Bm + b * sB;
#pragma unroll
      for (int j = 0; j < 4; ++j) {
        const float* p = Bf + (long)(col0 + 16 * j + lr) * K + k0 + lk;
        float4 u0 = *(const float4*)p;
        float4 u1 = *(const float4*)(p + 4);
        bf16x8 t;
        t[0] = (bf16)u0.x; t[1] = (bf16)u0.y; t[2] = (bf16)u0.z; t[3] = (bf16)u0.w;
        t[4] = (bf16)u1.x; t[5] = (bf16)u1.y; t[6] = (bf16)u1.z; t[7] = (bf16)u1.w;
        bb[j] = t;
      }
    }
#pragma unroll
    for (int i = 0; i < 4; ++i)
#pragma unroll
      for (int j = 0; j < 4; ++j)
        acc[i][j] = __builtin_amdgcn_mfma_f32_16x16x32_bf16(a[i], bb[j], acc[i][j], 0, 0, 0);
  }

  // epilogue: C/D layout col = l&15, row = (l>>4)*4 + reg
  int orow = (l >> 4) * 4;
  int ocol = l & 15;
#pragma unroll
  for (int i = 0; i < 4; ++i) {
#pragma unroll
    for (int j = 0; j < 4; ++j) {
      int colb = col0 + 16 * j + ocol;
#pragma unroll
      for (int r = 0; r < 4; ++r) {
        int row = row0 + 16 * i + orow + r;
        float vv = acc[i][j][r];
        if constexpr (BIAS_MODE == 1) vv += bias[colb];
        if constexpr (BIAS_MODE == 2) vv += bias[row];
        if constexpr (GATE_EPI) {
          float g = geb[(long)row * 4096 + colb];
          vv *= 1.f + 1.f / (1.f + __expf(-g));
        }
        long di = b * sD + (long)row * NC + colb;
        if constexpr (OUT_BF16)
          ((bf16*)D)[di] = (bf16)vv;
        else
          ((float*)D)[di] = vv;
      }
    }
  }
}

// ---------------------------------------------------------------------------
// gate: per row n (of B*N): s = <q, Wgg[0:256]> + <ge, Wgg[256:512]> + bgg
//       q += sigmoid(s) * ge     (q bf16 in place, ge fp32)
// 4 waves per block, one row per wave
// ---------------------------------------------------------------------------
__global__ __launch_bounds__(256) void gate_kernel(
    bf16* __restrict__ q, const float* __restrict__ ge,
    const float* __restrict__ Wgg, const float* __restrict__ bgg) {
  int row = blockIdx.x * 4 + (threadIdx.x >> 6);
  int l = threadIdx.x & 63;
  bf16* qr = q + (long)row * 256;
  const float* ger = ge + (long)row * 256;
  float s = 0.f;
  float qv[4], gv[4];
#pragma unroll
  for (int i = 0; i < 4; ++i) {
    int o = l + 64 * i;
    qv[i] = (float)qr[o];
    gv[i] = ger[o];
    s += qv[i] * Wgg[o] + gv[i] * Wgg[256 + o];
  }
#pragma unroll
  for (int m = 32; m >= 1; m >>= 1) s += __shfl_xor(s, m, 64);
  float gate = 1.f / (1.f + __expf(-(s + bgg[0])));
#pragma unroll
  for (int i = 0; i < 4; ++i) {
    int o = l + 64 * i;
    qr[o] = (bf16)(qv[i] + gate * gv[i]);
  }
}

// ---------------------------------------------------------------------------
// row softmax in place over 4096 columns, one block (256 thr) per row
// ---------------------------------------------------------------------------
__global__ __launch_bounds__(256) void softmax_kernel(float* __restrict__ attn) {
  long row = blockIdx.x;
  float* p = attn + row * 4096;
  int t = threadIdx.x;
  __shared__ float red[8];
  float4 v[4];
  float mx = -1e30f;
#pragma unroll
  for (int c = 0; c < 4; ++c) {
    v[c] = *(const float4*)(p + c * 1024 + t * 4);
    mx = fmaxf(mx, fmaxf(fmaxf(v[c].x, v[c].y), fmaxf(v[c].z, v[c].w)));
  }
#pragma unroll
  for (int m = 32; m >= 1; m >>= 1) mx = fmaxf(mx, __shfl_xor(mx, m, 64));
  if ((t & 63) == 0) red[t >> 6] = mx;
  __syncthreads();
  mx = fmaxf(fmaxf(red[0], red[1]), fmaxf(red[2], red[3]));
  float sum = 0.f;
#pragma unroll
  for (int c = 0; c < 4; ++c) {
    v[c].x = __expf(v[c].x - mx);
    v[c].y = __expf(v[c].y - mx);
    v[c].z = __expf(v[c].z - mx);
    v[c].w = __expf(v[c].w - mx);
    sum += v[c].x + v[c].y + v[c].z + v[c].w;
  }
#pragma unroll
  for (int m = 32; m >= 1; m >>= 1) sum += __shfl_xor(sum, m, 64);
  if ((t & 63) == 0) red[4 + (t >> 6)] = sum;
  __syncthreads();
  float inv = 1.f / (red[4] + red[5] + red[6] + red[7]);
#pragma unroll
  for (int c = 0; c < 4; ++c) {
    v[c].x *= inv; v[c].y *= inv; v[c].z *= inv; v[c].w *= inv;
    *(float4*)(p + c * 1024 + t * 4) = v[c];
  }
}

// ---------------------------------------------------------------------------
extern "C" void kernel_launch(void* const* d_in, const int* in_sizes, int n_in,
                              void* d_out, int out_size, void* d_ws, size_t ws_size,
                              hipStream_t stream) {
  const float* x    = (const float*)d_in[0];
  const float* geo  = (const float*)d_in[1];
  const float* Wq   = (const float*)d_in[2];
  const float* bq   = (const float*)d_in[3];
  const float* Wk   = (const float*)d_in[4];
  const float* bk   = (const float*)d_in[5];
  const float* Wv   = (const float*)d_in[6];
  const float* bv   = (const float*)d_in[7];
  const float* Wgp  = (const float*)d_in[8];
  const float* bgp  = (const float*)d_in[9];
  const float* Wgg  = (const float*)d_in[10];
  const float* bgg  = (const float*)d_in[11];

  float* out  = (float*)d_out;                    // [B][C][N]
  float* attn = out + (long)BB * CC * NN;         // [B][N][N]

  // workspace carve (256B aligned)
  char* w = (char*)d_ws;
  auto alloc = [&](size_t bytes) {
    char* p = w;
    w += (bytes + 255) & ~(size_t)255;
    return p;
  };
  bf16*  xt   = (bf16*)alloc((size_t)BB * NN * CC * 2);  // [B][N][C]
  bf16*  geob = (bf16*)alloc((size_t)BB * NN * CC * 2);  // [B][N][C]
  bf16*  qn   = (bf16*)alloc((size_t)BB * NN * CC * 2);  // [B][N][O]
  bf16*  kn   = (bf16*)alloc((size_t)BB * NN * CC * 2);  // [B][N][O]
  bf16*  vb   = (bf16*)alloc((size_t)BB * CC * NN * 2);  // [B][O][N]
  float* ge   = (float*)alloc((size_t)BB * NN * CC * 4); // [B][N][O] fp32
  bf16*  Wqb  = (bf16*)alloc((size_t)CC * CC * 2);
  bf16*  Wkb  = (bf16*)alloc((size_t)CC * CC * 2);
  bf16*  Wvb  = (bf16*)alloc((size_t)CC * CC * 2);
  bf16*  Wgpb = (bf16*)alloc((size_t)CC * CC * 2);

  const long NCst = (long)NN * CC;  // 1,048,576
  const long NNst = (long)NN * NN;  // 16,777,216

  // converts
  cvt_f32_bf16_kernel<<<64, 256, 0, stream>>>(Wq, Wqb, (long)CC * CC);
  cvt_f32_bf16_kernel<<<64, 256, 0, stream>>>(Wk, Wkb, (long)CC * CC);
  cvt_f32_bf16_kernel<<<64, 256, 0, stream>>>(Wv, Wvb, (long)CC * CC);
  cvt_f32_bf16_kernel<<<64, 256, 0, stream>>>(Wgp, Wgpb, (long)CC * CC);
  cvt_f32_bf16_kernel<<<(BB * NCst) / 1024, 256, 0, stream>>>(geo, geob, BB * NCst);
  transpose_x_kernel<<<dim3(4, 64, BB), 256, 0, stream>>>(x, xt);

  // q = xt . Wq^T + bq  -> qn bf16  [N x 256]
  gemm_nt_kernel<1, false, true, false><<<dim3(2, 32, BB), 256, 0, stream>>>(
      xt, Wqb, bq, qn, nullptr, NN, CC, CC, NCst, 0, NCst, 0);
  // ge = geo . Wgp^T + bgp -> fp32
  gemm_nt_kernel<1, false, false, false><<<dim3(2, 32, BB), 256, 0, stream>>>(
      geob, Wgpb, bgp, ge, nullptr, NN, CC, CC, NCst, 0, NCst, 0);
  // k = xt . Wk^T + bk -> kn bf16
  gemm_nt_kernel<1, false, true, false><<<dim3(2, 32, BB), 256, 0, stream>>>(
      xt, Wkb, bk, kn, nullptr, NN, CC, CC, NCst, 0, NCst, 0);
  // gate update on qn
  gate_kernel<<<(BB * NN) / 4, 256, 0, stream>>>(qn, ge, Wgg, bgg);
  // v = Wv . xt^T + bv -> vb bf16 [256 x N]
  gemm_nt_kernel<2, false, true, false><<<dim3(32, 2, BB), 256, 0, stream>>>(
      Wvb, xt, bv, vb, nullptr, CC, NN, CC, 0, NCst, NCst, 0);
  // energy = qn . kn^T -> attn region fp32
  gemm_nt_kernel<0, false, false, false><<<dim3(32, 32, BB), 256, 0, stream>>>(
      qn, kn, nullptr, attn, nullptr, NN, NN, CC, NCst, NCst, NNst, 0);
  // softmax in place
  softmax_kernel<<<BB * NN, 256, 0, stream>>>(attn);
  // out = vb . attn^T, gated epilogue, fp32
  gemm_nt_kernel<0, true, false, true><<<dim3(32, 2, BB), 256, 0, stream>>>(
      vb, attn, nullptr, out, ge, CC, NN, NN, NCst, NNst, NCst, NCst);
}

// Round 2
// 393.677 us; speedup vs baseline: 1.2177x; 1.2177x over previous
//
#include <hip/hip_runtime.h>
#include <hip/hip_bf16.h>
#include <math.h>

// Problem constants
static constexpr int BB = 4;     // batch
static constexpr int CC = 256;   // channels
static constexpr int NN = 4096;  // pixels (64*64)

using bf16   = __bf16;
using bf16x8 = __attribute__((ext_vector_type(8))) __bf16;
using bf16x4 = __attribute__((ext_vector_type(4))) __bf16;
using f32x4  = __attribute__((ext_vector_type(4))) float;

// async global->LDS, 16B per lane (dest must be wave-uniform base + lane*16)
__device__ inline void gload_lds16(const void* g, void* l) {
  __builtin_amdgcn_global_load_lds(
      (const __attribute__((address_space(1))) void*)g,
      (__attribute__((address_space(3))) void*)l, 16, 0, 0);
}

// ---------------------------------------------------------------------------
// fp32 -> bf16 elementwise convert (n multiple of 4)
// ---------------------------------------------------------------------------
__global__ __launch_bounds__(256) void cvt_f32_bf16_kernel(
    const float* __restrict__ in, bf16* __restrict__ out, long n) {
  long i = ((long)blockIdx.x * blockDim.x + threadIdx.x) * 4;
  if (i >= n) return;
  float4 v = *(const float4*)(in + i);
  bf16x4 t;
  t[0] = (bf16)v.x; t[1] = (bf16)v.y; t[2] = (bf16)v.z; t[3] = (bf16)v.w;
  *(bf16x4*)(out + i) = t;
}

// ---------------------------------------------------------------------------
// transpose x [B][C][N] fp32 -> xt [B][N][C] bf16
// ---------------------------------------------------------------------------
__global__ __launch_bounds__(256) void transpose_x_kernel(
    const float* __restrict__ x, bf16* __restrict__ xt) {
  __shared__ float tile[64][65];
  int b  = blockIdx.z;
  int c0 = blockIdx.x * 64;
  int n0 = blockIdx.y * 64;
  const float* xp = x  + (long)b * CC * NN;
  bf16*       xtp = xt + (long)b * NN * CC;
  int tj = threadIdx.x & 63;
  int ti = threadIdx.x >> 6;
#pragma unroll
  for (int p = 0; p < 16; ++p) {
    int i = ti + p * 4;
    tile[i][tj] = xp[(long)(c0 + i) * NN + n0 + tj];
  }
  __syncthreads();
#pragma unroll
  for (int p = 0; p < 16; ++p) {
    int i = ti + p * 4;
    xtp[(long)(n0 + i) * CC + c0 + tj] = (bf16)tile[tj][i];
  }
}

// ---------------------------------------------------------------------------
// m97-structure NT GEMM: D[r][c] = sum_k A[r][k]*B[c][k]
// 128x128 block tile, BK=32, 4 waves (2x2), wave tile 64x64 (4x4 MFMA frags).
// A staged via global_load_lds (bf16). B: B_MODE 0 = bf16 global_load_lds,
// B_MODE 1 = fp32 global -> reg -> cvt -> ds_write (for fp32 attention).
// BIAS_MODE: 0 none, 1 bias[col], 2 bias[row]
// GATE_EPI: multiply by (1 + sigmoid(ge_flat[row*4096 + col])) per batch
// ---------------------------------------------------------------------------
template <int BIAS_MODE, int B_MODE, bool OUT_BF16, bool GATE_EPI>
__global__ __launch_bounds__(256) void gemm_nt_lds(
    const bf16* __restrict__ A, const void* __restrict__ Bm,
    const float* __restrict__ bias, void* __restrict__ D,
    const float* __restrict__ gefl,
    int Ncols, int K, long sA, long sB, long sD, long sGe) {
  __shared__ bf16 As[128 * 32];
  __shared__ bf16 Bs[128 * 32];
  const int b = blockIdx.z;
  const bf16* Ab = A + (long)b * sA;
  const float* geb = GATE_EPI ? (gefl + b * sGe) : nullptr;

  const int t   = threadIdx.x;
  const int wid = t >> 6;
  const int l   = t & 63;
  const int lr  = l & 15;
  const int lk  = (l >> 4) * 8;
  const int row0 = blockIdx.y * 128;
  const int col0 = blockIdx.x * 128;
  const int warow = (wid >> 1) * 64;
  const int wbcol = (wid & 1) * 64;

  // staging maps: bf16 tile = 128 rows x 4 chunks(16B); 2 issues of 64 rows
  const int srow = t >> 2;        // 0..63
  const int scol = (t & 3) * 8;   // element col of 8-elem chunk
  // fp32 B tile = 128 rows x 8 chunks(float4); 4 issues of 32 rows
  const int frow = t >> 3;        // 0..31
  const int fc4  = (t & 7) * 4;

  f32x4 acc[4][4];
#pragma unroll
  for (int i = 0; i < 4; ++i)
#pragma unroll
    for (int j = 0; j < 4; ++j) acc[i][j] = {0.f, 0.f, 0.f, 0.f};

  for (int k0 = 0; k0 < K; k0 += 32) {
    __syncthreads();
#pragma unroll
    for (int p = 0; p < 2; ++p)
      gload_lds16(Ab + (long)(row0 + srow + 64 * p) * K + k0 + scol,
                  As + ((p * 256 + t) * 8));
    if constexpr (B_MODE == 0) {
      const bf16* Bb = (const bf16*)Bm + (long)b * sB;
#pragma unroll
      for (int p = 0; p < 2; ++p)
        gload_lds16(Bb + (long)(col0 + srow + 64 * p) * K + k0 + scol,
                    Bs + ((p * 256 + t) * 8));
    } else {
      const float* Bf = (const float*)Bm + (long)b * sB;
#pragma unroll
      for (int p = 0; p < 4; ++p) {
        float4 u = *(const float4*)(Bf + (long)(col0 + frow + 32 * p) * K + k0 + fc4);
        bf16x4 tv;
        tv[0] = (bf16)u.x; tv[1] = (bf16)u.y; tv[2] = (bf16)u.z; tv[3] = (bf16)u.w;
        *(bf16x4*)(Bs + (frow + 32 * p) * 32 + fc4) = tv;
      }
    }
    __syncthreads();
    bf16x8 a[4], bb[4];
#pragma unroll
    for (int i = 0; i < 4; ++i)
      a[i] = *(const bf16x8*)(As + (warow + 16 * i + lr) * 32 + lk);
#pragma unroll
    for (int j = 0; j < 4; ++j)
      bb[j] = *(const bf16x8*)(Bs + (wbcol + 16 * j + lr) * 32 + lk);
#pragma unroll
    for (int i = 0; i < 4; ++i)
#pragma unroll
      for (int j = 0; j < 4; ++j)
        acc[i][j] = __builtin_amdgcn_mfma_f32_16x16x32_bf16(a[i], bb[j], acc[i][j], 0, 0, 0);
  }

  // epilogue: C/D layout col = l&15, row = (l>>4)*4 + reg
  const int orow = (l >> 4) * 4;
  const int ocol = l & 15;
#pragma unroll
  for (int i = 0; i < 4; ++i) {
#pragma unroll
    for (int j = 0; j < 4; ++j) {
      int colb = col0 + wbcol + 16 * j + ocol;
#pragma unroll
      for (int r = 0; r < 4; ++r) {
        int row = row0 + warow + 16 * i + orow + r;
        float vv = acc[i][j][r];
        if constexpr (BIAS_MODE == 1) vv += bias[colb];
        if constexpr (BIAS_MODE == 2) vv += bias[row];
        if constexpr (GATE_EPI) {
          float g = geb[(long)row * 4096 + colb];
          vv *= 1.f + 1.f / (1.f + __expf(-g));
        }
        long di = b * sD + (long)row * Ncols + colb;
        if constexpr (OUT_BF16)
          ((bf16*)D)[di] = (bf16)vv;
        else
          ((float*)D)[di] = vv;
      }
    }
  }
}

// ---------------------------------------------------------------------------
// gate: per row n: s = <q,Wgg[0:256]> + <ge,Wgg[256:512]> + bgg;
//       q += sigmoid(s)*ge   (q bf16 in place, ge fp32). One wave per row.
// ---------------------------------------------------------------------------
__global__ __launch_bounds__(256) void gate_kernel(
    bf16* __restrict__ q, const float* __restrict__ ge,
    const float* __restrict__ Wgg, const float* __restrict__ bgg) {
  int row = blockIdx.x * 4 + (threadIdx.x >> 6);
  int l = threadIdx.x & 63;
  bf16* qr = q + (long)row * 256;
  const float* ger = ge + (long)row * 256;
  float s = 0.f;
  float qv[4], gv[4];
#pragma unroll
  for (int i = 0; i < 4; ++i) {
    int o = l + 64 * i;
    qv[i] = (float)qr[o];
    gv[i] = ger[o];
    s += qv[i] * Wgg[o] + gv[i] * Wgg[256 + o];
  }
#pragma unroll
  for (int m = 32; m >= 1; m >>= 1) s += __shfl_xor(s, m, 64);
  float gate = 1.f / (1.f + __expf(-(s + bgg[0])));
#pragma unroll
  for (int i = 0; i < 4; ++i) {
    int o = l + 64 * i;
    qr[o] = (bf16)(qv[i] + gate * gv[i]);
  }
}

// ---------------------------------------------------------------------------
// row softmax over 4096 cols, one block per row. In-place fp32 on attn;
// optionally also writes a bf16 copy (for the PV GEMM's B operand).
// ---------------------------------------------------------------------------
template <bool WRITE_BF16>
__global__ __launch_bounds__(256) void softmax_kernel(
    float* __restrict__ attn, bf16* __restrict__ abf) {
  long row = blockIdx.x;
  float* p = attn + row * 4096;
  bf16* pb = WRITE_BF16 ? (abf + row * 4096) : nullptr;
  int t = threadIdx.x;
  __shared__ float red[8];
  float4 v[4];
  float mx = -1e30f;
#pragma unroll
  for (int c = 0; c < 4; ++c) {
    v[c] = *(const float4*)(p + c * 1024 + t * 4);
    mx = fmaxf(mx, fmaxf(fmaxf(v[c].x, v[c].y), fmaxf(v[c].z, v[c].w)));
  }
#pragma unroll
  for (int m = 32; m >= 1; m >>= 1) mx = fmaxf(mx, __shfl_xor(mx, m, 64));
  if ((t & 63) == 0) red[t >> 6] = mx;
  __syncthreads();
  mx = fmaxf(fmaxf(red[0], red[1]), fmaxf(red[2], red[3]));
  float sum = 0.f;
#pragma unroll
  for (int c = 0; c < 4; ++c) {
    v[c].x = __expf(v[c].x - mx);
    v[c].y = __expf(v[c].y - mx);
    v[c].z = __expf(v[c].z - mx);
    v[c].w = __expf(v[c].w - mx);
    sum += v[c].x + v[c].y + v[c].z + v[c].w;
  }
#pragma unroll
  for (int m = 32; m >= 1; m >>= 1) sum += __shfl_xor(sum, m, 64);
  if ((t & 63) == 0) red[4 + (t >> 6)] = sum;
  __syncthreads();
  float inv = 1.f / (red[4] + red[5] + red[6] + red[7]);
#pragma unroll
  for (int c = 0; c < 4; ++c) {
    v[c].x *= inv; v[c].y *= inv; v[c].z *= inv; v[c].w *= inv;
    *(float4*)(p + c * 1024 + t * 4) = v[c];
    if constexpr (WRITE_BF16) {
      bf16x4 tb;
      tb[0] = (bf16)v[c].x; tb[1] = (bf16)v[c].y;
      tb[2] = (bf16)v[c].z; tb[3] = (bf16)v[c].w;
      *(bf16x4*)(pb + c * 1024 + t * 4) = tb;
    }
  }
}

// ---------------------------------------------------------------------------
extern "C" void kernel_launch(void* const* d_in, const int* in_sizes, int n_in,
                              void* d_out, int out_size, void* d_ws, size_t ws_size,
                              hipStream_t stream) {
  const float* x    = (const float*)d_in[0];
  const float* geo  = (const float*)d_in[1];
  const float* Wq   = (const float*)d_in[2];
  const float* bq   = (const float*)d_in[3];
  const float* Wk   = (const float*)d_in[4];
  const float* bk   = (const float*)d_in[5];
  const float* Wv   = (const float*)d_in[6];
  const float* bv   = (const float*)d_in[7];
  const float* Wgp  = (const float*)d_in[8];
  const float* bgp  = (const float*)d_in[9];
  const float* Wgg  = (const float*)d_in[10];
  const float* bgg  = (const float*)d_in[11];

  float* out  = (float*)d_out;                    // [B][C][N]
  float* attn = out + (long)BB * CC * NN;         // [B][N][N]

  char* w = (char*)d_ws;
  size_t used = 0;
  auto alloc = [&](size_t bytes) {
    char* p = w + used;
    used += (bytes + 255) & ~(size_t)255;
    return p;
  };
  bf16*  xt   = (bf16*)alloc((size_t)BB * NN * CC * 2);  // [B][N][C]
  bf16*  geob = (bf16*)alloc((size_t)BB * NN * CC * 2);  // [B][N][C]
  bf16*  qn   = (bf16*)alloc((size_t)BB * NN * CC * 2);  // [B][N][O]
  bf16*  kn   = (bf16*)alloc((size_t)BB * NN * CC * 2);  // [B][N][O]
  bf16*  vb   = (bf16*)alloc((size_t)BB * CC * NN * 2);  // [B][O][N]
  float* ge   = (float*)alloc((size_t)BB * NN * CC * 4); // [B][N][O] fp32
  bf16*  Wqb  = (bf16*)alloc((size_t)CC * CC * 2);
  bf16*  Wkb  = (bf16*)alloc((size_t)CC * CC * 2);
  bf16*  Wvb  = (bf16*)alloc((size_t)CC * CC * 2);
  bf16*  Wgpb = (bf16*)alloc((size_t)CC * CC * 2);
  // bf16 attention copy (134MB) — only if workspace allows
  size_t abf_bytes = (size_t)BB * NN * NN * 2;
  bool big = (ws_size >= used + abf_bytes + 256);
  bf16* abf = big ? (bf16*)alloc(abf_bytes) : nullptr;

  const long NCst = (long)NN * CC;  // 1,048,576
  const long NNst = (long)NN * NN;  // 16,777,216

  // converts + transpose
  cvt_f32_bf16_kernel<<<64, 256, 0, stream>>>(Wq, Wqb, (long)CC * CC);
  cvt_f32_bf16_kernel<<<64, 256, 0, stream>>>(Wk, Wkb, (long)CC * CC);
  cvt_f32_bf16_kernel<<<64, 256, 0, stream>>>(Wv, Wvb, (long)CC * CC);
  cvt_f32_bf16_kernel<<<64, 256, 0, stream>>>(Wgp, Wgpb, (long)CC * CC);
  cvt_f32_bf16_kernel<<<(BB * NCst) / 1024, 256, 0, stream>>>(geo, geob, BB * NCst);
  transpose_x_kernel<<<dim3(4, 64, BB), 256, 0, stream>>>(x, xt);

  // q = xt . Wq^T + bq -> qn bf16
  gemm_nt_lds<1, 0, true, false><<<dim3(2, 32, BB), 256, 0, stream>>>(
      xt, Wqb, bq, qn, nullptr, CC, CC, NCst, 0, NCst, 0);
  // ge = geo . Wgp^T + bgp -> fp32
  gemm_nt_lds<1, 0, false, false><<<dim3(2, 32, BB), 256, 0, stream>>>(
      geob, Wgpb, bgp, ge, nullptr, CC, CC, NCst, 0, NCst, 0);
  // k = xt . Wk^T + bk -> kn bf16
  gemm_nt_lds<1, 0, true, false><<<dim3(2, 32, BB), 256, 0, stream>>>(
      xt, Wkb, bk, kn, nullptr, CC, CC, NCst, 0, NCst, 0);
  // gate update on qn
  gate_kernel<<<(BB * NN) / 4, 256, 0, stream>>>(qn, ge, Wgg, bgg);
  // v = Wv . xt^T + bv -> vb bf16 [256 x N]
  gemm_nt_lds<2, 0, true, false><<<dim3(32, 2, BB), 256, 0, stream>>>(
      Wvb, xt, bv, vb, nullptr, NN, CC, 0, NCst, NCst, 0);
  // energy = qn . kn^T -> attn region fp32
  gemm_nt_lds<0, 0, false, false><<<dim3(32, 32, BB), 256, 0, stream>>>(
      qn, kn, nullptr, attn, nullptr, NN, CC, NCst, NCst, NNst, 0);
  // softmax in place (+ bf16 copy if ws allows)
  if (big)
    softmax_kernel<true><<<BB * NN, 256, 0, stream>>>(attn, abf);
  else
    softmax_kernel<false><<<BB * NN, 256, 0, stream>>>(attn, nullptr);
  // out = vb . attn^T, gated epilogue, fp32
  if (big)
    gemm_nt_lds<0, 0, false, true><<<dim3(32, 2, BB), 256, 0, stream>>>(
        vb, abf, nullptr, out, ge, NN, NN, NCst, NNst, NCst, NCst);
  else
    gemm_nt_lds<0, 1, false, true><<<dim3(32, 2, BB), 256, 0, stream>>>(
        vb, attn, nullptr, out, ge, NN, NN, NCst, NNst, NCst, NCst);
}

// Round 3
// 370.565 us; speedup vs baseline: 1.2936x; 1.0624x over previous
//
#include <hip/hip_runtime.h>
#include <hip/hip_bf16.h>
#include <math.h>

// Problem constants
static constexpr int BB = 4;     // batch
static constexpr int CC = 256;   // channels
static constexpr int NN = 4096;  // pixels (64*64)

using bf16   = __bf16;
using f16    = _Float16;
using bf16x8 = __attribute__((ext_vector_type(8))) __bf16;
using bf16x4 = __attribute__((ext_vector_type(4))) __bf16;
using f16x8  = __attribute__((ext_vector_type(8))) _Float16;
using f32x4  = __attribute__((ext_vector_type(4))) float;

// async global->LDS, 16B per lane (dest must be wave-uniform base + lane*16)
__device__ inline void gload_lds16(const void* g, void* l) {
  __builtin_amdgcn_global_load_lds(
      (const __attribute__((address_space(1))) void*)g,
      (__attribute__((address_space(3))) void*)l, 16, 0, 0);
}

// XCD-aware bijective block remap (requires nwg % 8 == 0; all call sites OK).
// hw dispatch index (x fastest) -> contiguous work chunk per XCD.
__device__ inline void swz_bid(int& xb, int& yb, int& zb) {
  int gx = gridDim.x, gy = gridDim.y;
  int nwg = gx * gy * (int)gridDim.z;
  int flat = blockIdx.x + gx * (blockIdx.y + gy * blockIdx.z);
  int q = nwg >> 3;
  int w = (flat & 7) * q + (flat >> 3);
  xb = w % gx;
  int r = w / gx;
  yb = r % gy;
  zb = r / gy;
}

// ---------------------------------------------------------------------------
// all four weight matrices fp32 -> bf16 in one launch. grid (64, 4)
// ---------------------------------------------------------------------------
__global__ __launch_bounds__(256) void cvt_weights_kernel(
    const float* __restrict__ w0, const float* __restrict__ w1,
    const float* __restrict__ w2, const float* __restrict__ w3,
    bf16* __restrict__ out) {
  const float* srcs[4] = {w0, w1, w2, w3};
  const float* s = srcs[blockIdx.y];
  bf16* dst = out + (size_t)blockIdx.y * (CC * CC);
  int i = (blockIdx.x * 256 + threadIdx.x) * 4;
  float4 v = *(const float4*)(s + i);
  bf16x4 t;
  t[0] = (bf16)v.x; t[1] = (bf16)v.y; t[2] = (bf16)v.z; t[3] = (bf16)v.w;
  *(bf16x4*)(dst + i) = t;
}

// ---------------------------------------------------------------------------
// fp32 -> bf16 elementwise convert (n multiple of 4)
// ---------------------------------------------------------------------------
__global__ __launch_bounds__(256) void cvt_f32_bf16_kernel(
    const float* __restrict__ in, bf16* __restrict__ out, long n) {
  long i = ((long)blockIdx.x * blockDim.x + threadIdx.x) * 4;
  if (i >= n) return;
  float4 v = *(const float4*)(in + i);
  bf16x4 t;
  t[0] = (bf16)v.x; t[1] = (bf16)v.y; t[2] = (bf16)v.z; t[3] = (bf16)v.w;
  *(bf16x4*)(out + i) = t;
}

// ---------------------------------------------------------------------------
// transpose x [B][C][N] fp32 -> xt [B][N][C] bf16
// ---------------------------------------------------------------------------
__global__ __launch_bounds__(256) void transpose_x_kernel(
    const float* __restrict__ x, bf16* __restrict__ xt) {
  __shared__ float tile[64][65];
  int b  = blockIdx.z;
  int c0 = blockIdx.x * 64;
  int n0 = blockIdx.y * 64;
  const float* xp = x  + (long)b * CC * NN;
  bf16*       xtp = xt + (long)b * NN * CC;
  int tj = threadIdx.x & 63;
  int ti = threadIdx.x >> 6;
#pragma unroll
  for (int p = 0; p < 16; ++p) {
    int i = ti + p * 4;
    tile[i][tj] = xp[(long)(c0 + i) * NN + n0 + tj];
  }
  __syncthreads();
#pragma unroll
  for (int p = 0; p < 16; ++p) {
    int i = ti + p * 4;
    xtp[(long)(n0 + i) * CC + c0 + tj] = (bf16)tile[tj][i];
  }
}

// ---------------------------------------------------------------------------
// m97-structure NT GEMM: D[r][c] = sum_k A[r][k]*B[c][k]
// 128x128 block tile, BK=32, 4 waves (2x2), wave tile 64x64 (4x4 MFMA frags).
// B_MODE 0: bf16 B via global_load_lds; 1: fp32 B -> reg cvt -> ds_write.
// OUT_MODE: 0 fp32, 1 bf16, 2 fp16.  BIAS_MODE: 0 none, 1 bias[col], 2 bias[row]
// GATE_EPI: multiply by (1 + sigmoid(ge[row*4096+col])).  SWZ: XCD block remap.
// ---------------------------------------------------------------------------
template <int BIAS_MODE, int B_MODE, int OUT_MODE, bool GATE_EPI, bool SWZ>
__global__ __launch_bounds__(256) void gemm_nt_lds(
    const bf16* __restrict__ A, const void* __restrict__ Bm,
    const float* __restrict__ bias, void* __restrict__ D,
    const float* __restrict__ gefl,
    int Ncols, int K, long sA, long sB, long sD, long sGe) {
  __shared__ bf16 As[128 * 32];
  __shared__ bf16 Bs[128 * 32];
  int bx = blockIdx.x, by = blockIdx.y, bz = blockIdx.z;
  if constexpr (SWZ) swz_bid(bx, by, bz);
  const bf16* Ab = A + (long)bz * sA;
  const float* geb = GATE_EPI ? (gefl + bz * sGe) : nullptr;

  const int t   = threadIdx.x;
  const int wid = t >> 6;
  const int l   = t & 63;
  const int lr  = l & 15;
  const int lk  = (l >> 4) * 8;
  const int row0 = by * 128;
  const int col0 = bx * 128;
  const int warow = (wid >> 1) * 64;
  const int wbcol = (wid & 1) * 64;

  const int srow = t >> 2;        // 0..63
  const int scol = (t & 3) * 8;
  const int frow = t >> 3;        // 0..31  (fp32 B staging)
  const int fc4  = (t & 7) * 4;

  f32x4 acc[4][4];
#pragma unroll
  for (int i = 0; i < 4; ++i)
#pragma unroll
    for (int j = 0; j < 4; ++j) acc[i][j] = {0.f, 0.f, 0.f, 0.f};

  for (int k0 = 0; k0 < K; k0 += 32) {
    __syncthreads();
#pragma unroll
    for (int p = 0; p < 2; ++p)
      gload_lds16(Ab + (long)(row0 + srow + 64 * p) * K + k0 + scol,
                  As + ((p * 256 + t) * 8));
    if constexpr (B_MODE == 0) {
      const bf16* Bb = (const bf16*)Bm + (long)bz * sB;
#pragma unroll
      for (int p = 0; p < 2; ++p)
        gload_lds16(Bb + (long)(col0 + srow + 64 * p) * K + k0 + scol,
                    Bs + ((p * 256 + t) * 8));
    } else {
      const float* Bf = (const float*)Bm + (long)bz * sB;
#pragma unroll
      for (int p = 0; p < 4; ++p) {
        float4 u = *(const float4*)(Bf + (long)(col0 + frow + 32 * p) * K + k0 + fc4);
        bf16x4 tv;
        tv[0] = (bf16)u.x; tv[1] = (bf16)u.y; tv[2] = (bf16)u.z; tv[3] = (bf16)u.w;
        *(bf16x4*)(Bs + (frow + 32 * p) * 32 + fc4) = tv;
      }
    }
    __syncthreads();
    bf16x8 a[4], bb[4];
#pragma unroll
    for (int i = 0; i < 4; ++i)
      a[i] = *(const bf16x8*)(As + (warow + 16 * i + lr) * 32 + lk);
#pragma unroll
    for (int j = 0; j < 4; ++j)
      bb[j] = *(const bf16x8*)(Bs + (wbcol + 16 * j + lr) * 32 + lk);
#pragma unroll
    for (int i = 0; i < 4; ++i)
#pragma unroll
      for (int j = 0; j < 4; ++j)
        acc[i][j] = __builtin_amdgcn_mfma_f32_16x16x32_bf16(a[i], bb[j], acc[i][j], 0, 0, 0);
  }

  const int orow = (l >> 4) * 4;
  const int ocol = l & 15;
#pragma unroll
  for (int i = 0; i < 4; ++i) {
#pragma unroll
    for (int j = 0; j < 4; ++j) {
      int colb = col0 + wbcol + 16 * j + ocol;
#pragma unroll
      for (int r = 0; r < 4; ++r) {
        int row = row0 + warow + 16 * i + orow + r;
        float vv = acc[i][j][r];
        if constexpr (BIAS_MODE == 1) vv += bias[colb];
        if constexpr (BIAS_MODE == 2) vv += bias[row];
        if constexpr (GATE_EPI) {
          float g = geb[(long)row * 4096 + colb];
          vv *= 1.f + 1.f / (1.f + __expf(-g));
        }
        long di = bz * sD + (long)row * Ncols + colb;
        if constexpr (OUT_MODE == 0)
          ((float*)D)[di] = vv;
        else if constexpr (OUT_MODE == 1)
          ((bf16*)D)[di] = (bf16)vv;
        else
          ((f16*)D)[di] = (f16)vv;
      }
    }
  }
}

// ---------------------------------------------------------------------------
// PV GEMM, 8 waves, block tile 256x64, BK=32: out[c][m] = sum_n v[c][n]*P[m][n]
// A = v bf16 [256][4096], B = P bf16 rows (ld 4096). Gate epilogue. fp32 out.
// Attention is read exactly once (BM covers full C).
// ---------------------------------------------------------------------------
template <bool SWZ>
__global__ __launch_bounds__(512) void gemm_pv8(
    const bf16* __restrict__ V, const bf16* __restrict__ P,
    float* __restrict__ out, const float* __restrict__ ge) {
  __shared__ bf16 As[256 * 32];
  __shared__ bf16 Bs[64 * 32];
  int bx = blockIdx.x, by = blockIdx.y, bz = blockIdx.z;
  if constexpr (SWZ) swz_bid(bx, by, bz);
  const long NCst = (long)NN * CC;
  const long NNst = (long)NN * NN;
  const bf16* Vb = V + bz * NCst;
  const bf16* Pb = P + bz * NNst;
  const float* geb = ge + bz * NCst;
  float* ob = out + bz * NCst;
  const int col0 = bx * 64;

  const int t   = threadIdx.x;
  const int wid = t >> 6;     // 0..7
  const int l   = t & 63;
  const int lr  = l & 15;
  const int lk  = (l >> 4) * 8;
  const int wrow = wid * 32;

  const int srow = t >> 2;    // 0..127
  const int scol = (t & 3) * 8;

  f32x4 acc[2][4];
#pragma unroll
  for (int i = 0; i < 2; ++i)
#pragma unroll
    for (int j = 0; j < 4; ++j) acc[i][j] = {0.f, 0.f, 0.f, 0.f};

  for (int k0 = 0; k0 < NN; k0 += 32) {
    __syncthreads();
#pragma unroll
    for (int p = 0; p < 2; ++p)
      gload_lds16(Vb + (long)(srow + 128 * p) * NN + k0 + scol,
                  As + ((p * 512 + t) * 8));
    if (t < 256)
      gload_lds16(Pb + (long)(col0 + srow) * NN + k0 + scol, Bs + t * 8);
    __syncthreads();
    bf16x8 a[2], bb[4];
#pragma unroll
    for (int i = 0; i < 2; ++i)
      a[i] = *(const bf16x8*)(As + (wrow + 16 * i + lr) * 32 + lk);
#pragma unroll
    for (int j = 0; j < 4; ++j)
      bb[j] = *(const bf16x8*)(Bs + (16 * j + lr) * 32 + lk);
#pragma unroll
    for (int i = 0; i < 2; ++i)
#pragma unroll
      for (int j = 0; j < 4; ++j)
        acc[i][j] = __builtin_amdgcn_mfma_f32_16x16x32_bf16(a[i], bb[j], acc[i][j], 0, 0, 0);
  }

  const int orow = (l >> 4) * 4;
  const int ocol = l & 15;
#pragma unroll
  for (int i = 0; i < 2; ++i) {
#pragma unroll
    for (int j = 0; j < 4; ++j) {
      int colb = col0 + 16 * j + ocol;
#pragma unroll
      for (int r = 0; r < 4; ++r) {
        int row = wrow + 16 * i + orow + r;
        float g = geb[(long)row * 4096 + colb];
        float vv = acc[i][j][r] * (1.f + 1.f / (1.f + __expf(-g)));
        ob[(long)row * 4096 + colb] = vv;
      }
    }
  }
}

// ---------------------------------------------------------------------------
// gate: per row n: s = <q,Wgg[0:256]> + <ge,Wgg[256:512]> + bgg;
//       q += sigmoid(s)*ge   (q bf16 in place, ge fp32). One wave per row.
// ---------------------------------------------------------------------------
__global__ __launch_bounds__(256) void gate_kernel(
    bf16* __restrict__ q, const float* __restrict__ ge,
    const float* __restrict__ Wgg, const float* __restrict__ bgg) {
  int row = blockIdx.x * 4 + (threadIdx.x >> 6);
  int l = threadIdx.x & 63;
  bf16* qr = q + (long)row * 256;
  const float* ger = ge + (long)row * 256;
  float s = 0.f;
  float qv[4], gv[4];
#pragma unroll
  for (int i = 0; i < 4; ++i) {
    int o = l + 64 * i;
    qv[i] = (float)qr[o];
    gv[i] = ger[o];
    s += qv[i] * Wgg[o] + gv[i] * Wgg[256 + o];
  }
#pragma unroll
  for (int m = 32; m >= 1; m >>= 1) s += __shfl_xor(s, m, 64);
  float gate = 1.f / (1.f + __expf(-(s + bgg[0])));
#pragma unroll
  for (int i = 0; i < 4; ++i) {
    int o = l + 64 * i;
    qr[o] = (bf16)(qv[i] + gate * gv[i]);
  }
}

// ---------------------------------------------------------------------------
// row softmax over 4096 cols, one block (256 thr) per row.
// MODE 0: fp32 in-place on attn (fallback path).
// MODE 1: read fp16 energy from aux, write fp32 attn + bf16 attn into aux
//         (in place, same bytes).
// ---------------------------------------------------------------------------
template <int MODE>
__global__ __launch_bounds__(256) void softmax_kernel(
    float* __restrict__ attn, void* __restrict__ aux) {
  long row = blockIdx.x;
  int t = threadIdx.x;
  __shared__ float red[8];
  if constexpr (MODE == 0) {
    float* p = attn + row * 4096;
    float4 v[4];
    float mx = -1e30f;
#pragma unroll
    for (int c = 0; c < 4; ++c) {
      v[c] = *(const float4*)(p + c * 1024 + t * 4);
      mx = fmaxf(mx, fmaxf(fmaxf(v[c].x, v[c].y), fmaxf(v[c].z, v[c].w)));
    }
#pragma unroll
    for (int m = 32; m >= 1; m >>= 1) mx = fmaxf(mx, __shfl_xor(mx, m, 64));
    if ((t & 63) == 0) red[t >> 6] = mx;
    __syncthreads();
    mx = fmaxf(fmaxf(red[0], red[1]), fmaxf(red[2], red[3]));
    float sum = 0.f;
#pragma unroll
    for (int c = 0; c < 4; ++c) {
      v[c].x = __expf(v[c].x - mx);
      v[c].y = __expf(v[c].y - mx);
      v[c].z = __expf(v[c].z - mx);
      v[c].w = __expf(v[c].w - mx);
      sum += v[c].x + v[c].y + v[c].z + v[c].w;
    }
#pragma unroll
    for (int m = 32; m >= 1; m >>= 1) sum += __shfl_xor(sum, m, 64);
    if ((t & 63) == 0) red[4 + (t >> 6)] = sum;
    __syncthreads();
    float inv = 1.f / (red[4] + red[5] + red[6] + red[7]);
#pragma unroll
    for (int c = 0; c < 4; ++c) {
      v[c].x *= inv; v[c].y *= inv; v[c].z *= inv; v[c].w *= inv;
      *(float4*)(p + c * 1024 + t * 4) = v[c];
    }
  } else {
    const f16* pe = (const f16*)aux + row * 4096;
    float* pa = attn + row * 4096;
    bf16* pb = (bf16*)aux + row * 4096;
    float v[16];
    f16x8 e0 = *(const f16x8*)(pe + t * 16);
    f16x8 e1 = *(const f16x8*)(pe + t * 16 + 8);
    float mx = -1e30f;
#pragma unroll
    for (int i = 0; i < 8; ++i) { v[i] = (float)e0[i]; v[8 + i] = (float)e1[i]; }
#pragma unroll
    for (int i = 0; i < 16; ++i) mx = fmaxf(mx, v[i]);
#pragma unroll
    for (int m = 32; m >= 1; m >>= 1) mx = fmaxf(mx, __shfl_xor(mx, m, 64));
    if ((t & 63) == 0) red[t >> 6] = mx;
    __syncthreads();
    mx = fmaxf(fmaxf(red[0], red[1]), fmaxf(red[2], red[3]));
    float sum = 0.f;
#pragma unroll
    for (int i = 0; i < 16; ++i) { v[i] = __expf(v[i] - mx); sum += v[i]; }
#pragma unroll
    for (int m = 32; m >= 1; m >>= 1) sum += __shfl_xor(sum, m, 64);
    if ((t & 63) == 0) red[4 + (t >> 6)] = sum;
    __syncthreads();
    float inv = 1.f / (red[4] + red[5] + red[6] + red[7]);
#pragma unroll
    for (int i = 0; i < 16; ++i) v[i] *= inv;
#pragma unroll
    for (int c = 0; c < 4; ++c) {
      float4 u = {v[4 * c], v[4 * c + 1], v[4 * c + 2], v[4 * c + 3]};
      *(float4*)(pa + t * 16 + c * 4) = u;
    }
    bf16x8 b0, b1;
#pragma unroll
    for (int i = 0; i < 8; ++i) { b0[i] = (bf16)v[i]; b1[i] = (bf16)v[8 + i]; }
    *(bf16x8*)(pb + t * 16)     = b0;
    *(bf16x8*)(pb + t * 16 + 8) = b1;
  }
}

// ---------------------------------------------------------------------------
extern "C" void kernel_launch(void* const* d_in, const int* in_sizes, int n_in,
                              void* d_out, int out_size, void* d_ws, size_t ws_size,
                              hipStream_t stream) {
  const float* x    = (const float*)d_in[0];
  const float* geo  = (const float*)d_in[1];
  const float* Wq   = (const float*)d_in[2];
  const float* bq   = (const float*)d_in[3];
  const float* Wk   = (const float*)d_in[4];
  const float* bk   = (const float*)d_in[5];
  const float* Wv   = (const float*)d_in[6];
  const float* bv   = (const float*)d_in[7];
  const float* Wgp  = (const float*)d_in[8];
  const float* bgp  = (const float*)d_in[9];
  const float* Wgg  = (const float*)d_in[10];
  const float* bgg  = (const float*)d_in[11];

  float* out  = (float*)d_out;                    // [B][C][N]
  float* attn = out + (long)BB * CC * NN;         // [B][N][N]

  char* w = (char*)d_ws;
  size_t used = 0;
  auto alloc = [&](size_t bytes) {
    char* p = w + used;
    used += (bytes + 255) & ~(size_t)255;
    return p;
  };
  bf16*  xt   = (bf16*)alloc((size_t)BB * NN * CC * 2);  // [B][N][C]
  bf16*  geob = (bf16*)alloc((size_t)BB * NN * CC * 2);  // [B][N][C]
  bf16*  qn   = (bf16*)alloc((size_t)BB * NN * CC * 2);  // [B][N][O]
  bf16*  kn   = (bf16*)alloc((size_t)BB * NN * CC * 2);  // [B][N][O]
  bf16*  vb   = (bf16*)alloc((size_t)BB * CC * NN * 2);  // [B][O][N]
  float* ge   = (float*)alloc((size_t)BB * NN * CC * 4); // [B][N][O] fp32
  bf16*  Wall = (bf16*)alloc((size_t)4 * CC * CC * 2);
  bf16*  Wqb  = Wall;
  bf16*  Wkb  = Wall + CC * CC;
  bf16*  Wvb  = Wall + 2 * CC * CC;
  bf16*  Wgpb = Wall + 3 * CC * CC;
  // fp16 energy / bf16 attention buffer (134MB) — only if workspace allows
  size_t abf_bytes = (size_t)BB * NN * NN * 2;
  bool big = (ws_size >= used + abf_bytes + 256);
  void* abf = big ? (void*)alloc(abf_bytes) : nullptr;

  const long NCst = (long)NN * CC;  // 1,048,576
  const long NNst = (long)NN * NN;  // 16,777,216

  // converts + transpose
  cvt_weights_kernel<<<dim3(64, 4), 256, 0, stream>>>(Wq, Wk, Wv, Wgp, Wall);
  cvt_f32_bf16_kernel<<<(BB * NCst) / 1024, 256, 0, stream>>>(geo, geob, BB * NCst);
  transpose_x_kernel<<<dim3(4, 64, BB), 256, 0, stream>>>(x, xt);

  // q = xt . Wq^T + bq -> qn bf16
  gemm_nt_lds<1, 0, 1, false, false><<<dim3(2, 32, BB), 256, 0, stream>>>(
      xt, Wqb, bq, qn, nullptr, CC, CC, NCst, 0, NCst, 0);
  // ge = geo . Wgp^T + bgp -> fp32
  gemm_nt_lds<1, 0, 0, false, false><<<dim3(2, 32, BB), 256, 0, stream>>>(
      geob, Wgpb, bgp, ge, nullptr, CC, CC, NCst, 0, NCst, 0);
  // k = xt . Wk^T + bk -> kn bf16
  gemm_nt_lds<1, 0, 1, false, false><<<dim3(2, 32, BB), 256, 0, stream>>>(
      xt, Wkb, bk, kn, nullptr, CC, CC, NCst, 0, NCst, 0);
  // gate update on qn
  gate_kernel<<<(BB * NN) / 4, 256, 0, stream>>>(qn, ge, Wgg, bgg);
  // v = Wv . xt^T + bv -> vb bf16 [256 x N]
  gemm_nt_lds<2, 0, 1, false, false><<<dim3(32, 2, BB), 256, 0, stream>>>(
      Wvb, xt, bv, vb, nullptr, NN, CC, 0, NCst, NCst, 0);

  if (big) {
    // energy = qn . kn^T -> fp16 into abf
    gemm_nt_lds<0, 0, 2, false, true><<<dim3(32, 32, BB), 256, 0, stream>>>(
        qn, kn, nullptr, abf, nullptr, NN, CC, NCst, NCst, NNst, 0);
    // softmax: fp16 energy -> fp32 attn (d_out) + bf16 attn (abf, in place)
    softmax_kernel<1><<<BB * NN, 256, 0, stream>>>(attn, abf);
    // out = v . attn^T (bf16 attn), gated epilogue
    gemm_pv8<true><<<dim3(64, 1, BB), 512, 0, stream>>>(
        vb, (const bf16*)abf, out, ge);
  } else {
    gemm_nt_lds<0, 0, 0, false, true><<<dim3(32, 32, BB), 256, 0, stream>>>(
        qn, kn, nullptr, attn, nullptr, NN, CC, NCst, NCst, NNst, 0);
    softmax_kernel<0><<<BB * NN, 256, 0, stream>>>(attn, nullptr);
    gemm_nt_lds<0, 1, 0, true, true><<<dim3(32, 2, BB), 256, 0, stream>>>(
        vb, attn, nullptr, out, ge, NN, NN, NCst, NNst, NCst, NCst);
  }
}

// Round 4
// 308.452 us; speedup vs baseline: 1.5541x; 1.2014x over previous
//
#include <hip/hip_runtime.h>
#include <hip/hip_bf16.h>
#include <math.h>

// Problem constants
static constexpr int BB = 4;     // batch
static constexpr int CC = 256;   // channels
static constexpr int NN = 4096;  // pixels (64*64)

using bf16   = __bf16;
using f16    = _Float16;
using bf16x8 = __attribute__((ext_vector_type(8))) __bf16;
using bf16x4 = __attribute__((ext_vector_type(4))) __bf16;
using f16x8  = __attribute__((ext_vector_type(8))) _Float16;
using f16x4  = __attribute__((ext_vector_type(4))) _Float16;
using f32x4  = __attribute__((ext_vector_type(4))) float;

// async global->LDS, 16B per lane (dest must be wave-uniform base + lane*16)
__device__ inline void gload_lds16(const void* g, void* l) {
  __builtin_amdgcn_global_load_lds(
      (const __attribute__((address_space(1))) void*)g,
      (__attribute__((address_space(3))) void*)l, 16, 0, 0);
}

// XCD-aware bijective block remap (requires nwg % 8 == 0; all call sites OK).
__device__ inline void swz_bid(int& xb, int& yb, int& zb) {
  int gx = gridDim.x, gy = gridDim.y;
  int nwg = gx * gy * (int)gridDim.z;
  int flat = blockIdx.x + gx * (blockIdx.y + gy * blockIdx.z);
  int q = nwg >> 3;
  int w = (flat & 7) * q + (flat >> 3);
  xb = w % gx;
  int r = w / gx;
  yb = r % gy;
  zb = r / gy;
}

// ---------------------------------------------------------------------------
// all four weight matrices fp32 -> bf16 in one launch. grid (64, 4)
// ---------------------------------------------------------------------------
__global__ __launch_bounds__(256) void cvt_weights_kernel(
    const float* __restrict__ w0, const float* __restrict__ w1,
    const float* __restrict__ w2, const float* __restrict__ w3,
    bf16* __restrict__ out) {
  const float* srcs[4] = {w0, w1, w2, w3};
  const float* s = srcs[blockIdx.y];
  bf16* dst = out + (size_t)blockIdx.y * (CC * CC);
  int i = (blockIdx.x * 256 + threadIdx.x) * 4;
  float4 v = *(const float4*)(s + i);
  bf16x4 t;
  t[0] = (bf16)v.x; t[1] = (bf16)v.y; t[2] = (bf16)v.z; t[3] = (bf16)v.w;
  *(bf16x4*)(dst + i) = t;
}

// ---------------------------------------------------------------------------
// fp32 -> bf16 elementwise convert (n multiple of 4)
// ---------------------------------------------------------------------------
__global__ __launch_bounds__(256) void cvt_f32_bf16_kernel(
    const float* __restrict__ in, bf16* __restrict__ out, long n) {
  long i = ((long)blockIdx.x * blockDim.x + threadIdx.x) * 4;
  if (i >= n) return;
  float4 v = *(const float4*)(in + i);
  bf16x4 t;
  t[0] = (bf16)v.x; t[1] = (bf16)v.y; t[2] = (bf16)v.z; t[3] = (bf16)v.w;
  *(bf16x4*)(out + i) = t;
}

// ---------------------------------------------------------------------------
// transpose x [B][C][N] fp32 -> xt [B][N][C] bf16
// ---------------------------------------------------------------------------
__global__ __launch_bounds__(256) void transpose_x_kernel(
    const float* __restrict__ x, bf16* __restrict__ xt) {
  __shared__ float tile[64][65];
  int b  = blockIdx.z;
  int c0 = blockIdx.x * 64;
  int n0 = blockIdx.y * 64;
  const float* xp = x  + (long)b * CC * NN;
  bf16*       xtp = xt + (long)b * NN * CC;
  int tj = threadIdx.x & 63;
  int ti = threadIdx.x >> 6;
#pragma unroll
  for (int p = 0; p < 16; ++p) {
    int i = ti + p * 4;
    tile[i][tj] = xp[(long)(c0 + i) * NN + n0 + tj];
  }
  __syncthreads();
#pragma unroll
  for (int p = 0; p < 16; ++p) {
    int i = ti + p * 4;
    xtp[(long)(n0 + i) * CC + c0 + tj] = (bf16)tile[tj][i];
  }
}

// ---------------------------------------------------------------------------
// Fused 4-projection GEMM. blockIdx.z = b*4 + p, p in {0:q,1:ge,2:k,3:v}.
// p<3: D[row][col] = sum_k A[row][k]*W[col][k], row0=by*128 (M=4096),
//      col0=bx*128 (N=256). p==3: A=Wv (M=256, row0=bx*128), B=xt
//      (N=4096, col0=by*128), store [C][N].
// grid dim3(2,32,16), 256 threads, m97 structure.
// ---------------------------------------------------------------------------
__global__ __launch_bounds__(256) void proj_all_kernel(
    const bf16* __restrict__ xt, const bf16* __restrict__ geob,
    const bf16* __restrict__ Wall,
    const float* __restrict__ bq, const float* __restrict__ bgp,
    const float* __restrict__ bk, const float* __restrict__ bv,
    bf16* __restrict__ qn, float* __restrict__ ge,
    bf16* __restrict__ kn, bf16* __restrict__ vb) {
  __shared__ bf16 As[128 * 32];
  __shared__ bf16 Bs[128 * 32];
  const long NCst = (long)NN * CC;
  const int bz = blockIdx.z;
  const int b = bz >> 2, p = bz & 3;
  const bf16 *Ap, *Bp;
  const float* bias;
  int row0, col0;
  if (p == 3) {
    Ap = Wall + 2 * CC * CC;        // Wv
    Bp = xt + b * NCst;
    bias = bv;
    row0 = blockIdx.x * 128;        // 0..128  (M=256)
    col0 = blockIdx.y * 128;        // 0..3968 (N=4096)
  } else {
    Ap = (p == 1 ? geob : xt) + b * NCst;
    Bp = Wall + (size_t)(p == 0 ? 0 : (p == 1 ? 3 : 1)) * CC * CC;
    bias = (p == 0 ? bq : (p == 1 ? bgp : bk));
    row0 = blockIdx.y * 128;
    col0 = blockIdx.x * 128;
  }

  const int t   = threadIdx.x;
  const int wid = t >> 6;
  const int l   = t & 63;
  const int lr  = l & 15;
  const int lk  = (l >> 4) * 8;
  const int warow = (wid >> 1) * 64;
  const int wbcol = (wid & 1) * 64;
  const int srow = t >> 2;
  const int scol = (t & 3) * 8;

  f32x4 acc[4][4];
#pragma unroll
  for (int i = 0; i < 4; ++i)
#pragma unroll
    for (int j = 0; j < 4; ++j) acc[i][j] = {0.f, 0.f, 0.f, 0.f};

  for (int k0 = 0; k0 < CC; k0 += 32) {
    __syncthreads();
#pragma unroll
    for (int q = 0; q < 2; ++q)
      gload_lds16(Ap + (long)(row0 + srow + 64 * q) * CC + k0 + scol,
                  As + ((q * 256 + t) * 8));
#pragma unroll
    for (int q = 0; q < 2; ++q)
      gload_lds16(Bp + (long)(col0 + srow + 64 * q) * CC + k0 + scol,
                  Bs + ((q * 256 + t) * 8));
    __syncthreads();
    bf16x8 a[4], bb[4];
#pragma unroll
    for (int i = 0; i < 4; ++i)
      a[i] = *(const bf16x8*)(As + (warow + 16 * i + lr) * 32 + lk);
#pragma unroll
    for (int j = 0; j < 4; ++j)
      bb[j] = *(const bf16x8*)(Bs + (wbcol + 16 * j + lr) * 32 + lk);
#pragma unroll
    for (int i = 0; i < 4; ++i)
#pragma unroll
      for (int j = 0; j < 4; ++j)
        acc[i][j] = __builtin_amdgcn_mfma_f32_16x16x32_bf16(a[i], bb[j], acc[i][j], 0, 0, 0);
  }

  const int orow = (l >> 4) * 4;
  const int ocol = l & 15;
#pragma unroll
  for (int i = 0; i < 4; ++i) {
#pragma unroll
    for (int j = 0; j < 4; ++j) {
      int colb = col0 + wbcol + 16 * j + ocol;
#pragma unroll
      for (int r = 0; r < 4; ++r) {
        int row = row0 + warow + 16 * i + orow + r;
        if (p == 3) {
          float vv = acc[i][j][r] + bias[row];
          vb[b * NCst + (long)row * NN + colb] = (bf16)vv;
        } else {
          float vv = acc[i][j][r] + bias[colb];
          long di = b * NCst + (long)row * CC + colb;
          if (p == 1)
            ge[di] = vv;
          else
            (p == 0 ? qn : kn)[di] = (bf16)vv;
        }
      }
    }
  }
}

// ---------------------------------------------------------------------------
// m97-structure NT GEMM (energy + fallbacks): D[r][c] = sum_k A[r][k]*B[c][k]
// ---------------------------------------------------------------------------
template <int BIAS_MODE, int B_MODE, int OUT_MODE, bool GATE_EPI, bool SWZ>
__global__ __launch_bounds__(256) void gemm_nt_lds(
    const bf16* __restrict__ A, const void* __restrict__ Bm,
    const float* __restrict__ bias, void* __restrict__ D,
    const float* __restrict__ gefl,
    int Ncols, int K, long sA, long sB, long sD, long sGe) {
  __shared__ bf16 As[128 * 32];
  __shared__ bf16 Bs[128 * 32];
  int bx = blockIdx.x, by = blockIdx.y, bz = blockIdx.z;
  if constexpr (SWZ) swz_bid(bx, by, bz);
  const bf16* Ab = A + (long)bz * sA;
  const float* geb = GATE_EPI ? (gefl + bz * sGe) : nullptr;

  const int t   = threadIdx.x;
  const int wid = t >> 6;
  const int l   = t & 63;
  const int lr  = l & 15;
  const int lk  = (l >> 4) * 8;
  const int row0 = by * 128;
  const int col0 = bx * 128;
  const int warow = (wid >> 1) * 64;
  const int wbcol = (wid & 1) * 64;

  const int srow = t >> 2;
  const int scol = (t & 3) * 8;
  const int frow = t >> 3;
  const int fc4  = (t & 7) * 4;

  f32x4 acc[4][4];
#pragma unroll
  for (int i = 0; i < 4; ++i)
#pragma unroll
    for (int j = 0; j < 4; ++j) acc[i][j] = {0.f, 0.f, 0.f, 0.f};

  for (int k0 = 0; k0 < K; k0 += 32) {
    __syncthreads();
#pragma unroll
    for (int p = 0; p < 2; ++p)
      gload_lds16(Ab + (long)(row0 + srow + 64 * p) * K + k0 + scol,
                  As + ((p * 256 + t) * 8));
    if constexpr (B_MODE == 0) {
      const bf16* Bb = (const bf16*)Bm + (long)bz * sB;
#pragma unroll
      for (int p = 0; p < 2; ++p)
        gload_lds16(Bb + (long)(col0 + srow + 64 * p) * K + k0 + scol,
                    Bs + ((p * 256 + t) * 8));
    } else {
      const float* Bf = (const float*)Bm + (long)bz * sB;
#pragma unroll
      for (int p = 0; p < 4; ++p) {
        float4 u = *(const float4*)(Bf + (long)(col0 + frow + 32 * p) * K + k0 + fc4);
        bf16x4 tv;
        tv[0] = (bf16)u.x; tv[1] = (bf16)u.y; tv[2] = (bf16)u.z; tv[3] = (bf16)u.w;
        *(bf16x4*)(Bs + (frow + 32 * p) * 32 + fc4) = tv;
      }
    }
    __syncthreads();
    bf16x8 a[4], bb[4];
#pragma unroll
    for (int i = 0; i < 4; ++i)
      a[i] = *(const bf16x8*)(As + (warow + 16 * i + lr) * 32 + lk);
#pragma unroll
    for (int j = 0; j < 4; ++j)
      bb[j] = *(const bf16x8*)(Bs + (wbcol + 16 * j + lr) * 32 + lk);
#pragma unroll
    for (int i = 0; i < 4; ++i)
#pragma unroll
      for (int j = 0; j < 4; ++j)
        acc[i][j] = __builtin_amdgcn_mfma_f32_16x16x32_bf16(a[i], bb[j], acc[i][j], 0, 0, 0);
  }

  const int orow = (l >> 4) * 4;
  const int ocol = l & 15;
#pragma unroll
  for (int i = 0; i < 4; ++i) {
#pragma unroll
    for (int j = 0; j < 4; ++j) {
      int colb = col0 + wbcol + 16 * j + ocol;
#pragma unroll
      for (int r = 0; r < 4; ++r) {
        int row = row0 + warow + 16 * i + orow + r;
        float vv = acc[i][j][r];
        if constexpr (BIAS_MODE == 1) vv += bias[colb];
        if constexpr (BIAS_MODE == 2) vv += bias[row];
        if constexpr (GATE_EPI) {
          float g = geb[(long)row * 4096 + colb];
          vv *= 1.f + 1.f / (1.f + __expf(-g));
        }
        long di = bz * sD + (long)row * Ncols + colb;
        if constexpr (OUT_MODE == 0)
          ((float*)D)[di] = vv;
        else if constexpr (OUT_MODE == 1)
          ((bf16*)D)[di] = (bf16)vv;
        else
          ((f16*)D)[di] = (f16)vv;
      }
    }
  }
}

// ---------------------------------------------------------------------------
// row stats: per attention row, m = max(e), inv = 1/sum(exp(e-m)).
// One block (256 thr) per row; fp16 energy in, float2 {m, inv} out.
// ---------------------------------------------------------------------------
__global__ __launch_bounds__(256) void rowstat_kernel(
    const f16* __restrict__ e, float2* __restrict__ minv) {
  long row = blockIdx.x;
  const f16* pe = e + row * 4096;
  int t = threadIdx.x;
  __shared__ float red[8];
  float v[16];
  f16x8 e0 = *(const f16x8*)(pe + t * 16);
  f16x8 e1 = *(const f16x8*)(pe + t * 16 + 8);
#pragma unroll
  for (int i = 0; i < 8; ++i) { v[i] = (float)e0[i]; v[8 + i] = (float)e1[i]; }
  float mx = v[0];
#pragma unroll
  for (int i = 1; i < 16; ++i) mx = fmaxf(mx, v[i]);
#pragma unroll
  for (int m = 32; m >= 1; m >>= 1) mx = fmaxf(mx, __shfl_xor(mx, m, 64));
  if ((t & 63) == 0) red[t >> 6] = mx;
  __syncthreads();
  mx = fmaxf(fmaxf(red[0], red[1]), fmaxf(red[2], red[3]));
  float sum = 0.f;
#pragma unroll
  for (int i = 0; i < 16; ++i) sum += __expf(v[i] - mx);
#pragma unroll
  for (int m = 32; m >= 1; m >>= 1) sum += __shfl_xor(sum, m, 64);
  if ((t & 63) == 0) red[4 + (t >> 6)] = sum;
  __syncthreads();
  if (t == 0) {
    float s = red[4] + red[5] + red[6] + red[7];
    minv[row] = make_float2(mx, 1.f / s);
  }
}

// ---------------------------------------------------------------------------
// Fused softmax+PV GEMM, 8 waves, block tile 256x64 (full C), BK=32.
// out[c][m] = sum_n v[c][n] * p[m][n], p = exp(e-m_row)*inv_row computed
// on the fly from fp16 energy; fp32 p also written to attn (required output).
// Gate epilogue on out. Each attention element produced+consumed exactly once.
// ---------------------------------------------------------------------------
template <bool SWZ>
__global__ __launch_bounds__(512) void pv_fused_kernel(
    const bf16* __restrict__ V, const f16* __restrict__ E,
    const float2* __restrict__ minv, float* __restrict__ attn,
    float* __restrict__ out, const float* __restrict__ ge) {
  __shared__ bf16 As[256 * 32];
  __shared__ bf16 Bs[64 * 32];
  int bx = blockIdx.x, by = blockIdx.y, bz = blockIdx.z;
  if constexpr (SWZ) swz_bid(bx, by, bz);
  const long NCst = (long)NN * CC;
  const long NNst = (long)NN * NN;
  const bf16* Vb = V + bz * NCst;
  const f16*  Eb = E + bz * NNst;
  float* Ab_attn = attn + bz * NNst;
  const float* geb = ge + bz * NCst;
  float* ob = out + bz * NCst;
  const int col0 = bx * 64;

  const int t   = threadIdx.x;
  const int wid = t >> 6;
  const int l   = t & 63;
  const int lr  = l & 15;
  const int lk  = (l >> 4) * 8;
  const int wrow = wid * 32;

  const int srow = t >> 2;        // 0..127 (V staging)
  const int scol = (t & 3) * 8;
  const int erow = t >> 3;        // 0..63  (energy staging row)
  const int ec4  = (t & 7) * 4;   // energy col chunk (4 elems)

  const float2 mi = minv[(long)bz * NN + col0 + erow];

  f32x4 acc[2][4];
#pragma unroll
  for (int i = 0; i < 2; ++i)
#pragma unroll
    for (int j = 0; j < 4; ++j) acc[i][j] = {0.f, 0.f, 0.f, 0.f};

  for (int k0 = 0; k0 < NN; k0 += 32) {
    __syncthreads();
#pragma unroll
    for (int p = 0; p < 2; ++p)
      gload_lds16(Vb + (long)(srow + 128 * p) * NN + k0 + scol,
                  As + ((p * 512 + t) * 8));
    {
      f16x4 ev = *(const f16x4*)(Eb + (long)(col0 + erow) * NN + k0 + ec4);
      float4 pv;
      pv.x = __expf((float)ev[0] - mi.x) * mi.y;
      pv.y = __expf((float)ev[1] - mi.x) * mi.y;
      pv.z = __expf((float)ev[2] - mi.x) * mi.y;
      pv.w = __expf((float)ev[3] - mi.x) * mi.y;
      *(float4*)(Ab_attn + (long)(col0 + erow) * NN + k0 + ec4) = pv;
      bf16x4 pb;
      pb[0] = (bf16)pv.x; pb[1] = (bf16)pv.y;
      pb[2] = (bf16)pv.z; pb[3] = (bf16)pv.w;
      *(bf16x4*)(Bs + erow * 32 + ec4) = pb;
    }
    __syncthreads();
    bf16x8 a[2], bb[4];
#pragma unroll
    for (int i = 0; i < 2; ++i)
      a[i] = *(const bf16x8*)(As + (wrow + 16 * i + lr) * 32 + lk);
#pragma unroll
    for (int j = 0; j < 4; ++j)
      bb[j] = *(const bf16x8*)(Bs + (16 * j + lr) * 32 + lk);
#pragma unroll
    for (int i = 0; i < 2; ++i)
#pragma unroll
      for (int j = 0; j < 4; ++j)
        acc[i][j] = __builtin_amdgcn_mfma_f32_16x16x32_bf16(a[i], bb[j], acc[i][j], 0, 0, 0);
  }

  const int orow = (l >> 4) * 4;
  const int ocol = l & 15;
#pragma unroll
  for (int i = 0; i < 2; ++i) {
#pragma unroll
    for (int j = 0; j < 4; ++j) {
      int colb = col0 + 16 * j + ocol;
#pragma unroll
      for (int r = 0; r < 4; ++r) {
        int row = wrow + 16 * i + orow + r;
        float g = geb[(long)row * 4096 + colb];
        float vv = acc[i][j][r] * (1.f + 1.f / (1.f + __expf(-g)));
        ob[(long)row * 4096 + colb] = vv;
      }
    }
  }
}

// ---------------------------------------------------------------------------
// gate: per row n: s = <q,Wgg[0:256]> + <ge,Wgg[256:512]> + bgg;
//       q += sigmoid(s)*ge   (q bf16 in place, ge fp32). One wave per row.
// ---------------------------------------------------------------------------
__global__ __launch_bounds__(256) void gate_kernel(
    bf16* __restrict__ q, const float* __restrict__ ge,
    const float* __restrict__ Wgg, const float* __restrict__ bgg) {
  int row = blockIdx.x * 4 + (threadIdx.x >> 6);
  int l = threadIdx.x & 63;
  bf16* qr = q + (long)row * 256;
  const float* ger = ge + (long)row * 256;
  float s = 0.f;
  float qv[4], gv[4];
#pragma unroll
  for (int i = 0; i < 4; ++i) {
    int o = l + 64 * i;
    qv[i] = (float)qr[o];
    gv[i] = ger[o];
    s += qv[i] * Wgg[o] + gv[i] * Wgg[256 + o];
  }
#pragma unroll
  for (int m = 32; m >= 1; m >>= 1) s += __shfl_xor(s, m, 64);
  float gate = 1.f / (1.f + __expf(-(s + bgg[0])));
#pragma unroll
  for (int i = 0; i < 4; ++i) {
    int o = l + 64 * i;
    qr[o] = (bf16)(qv[i] + gate * gv[i]);
  }
}

// ---------------------------------------------------------------------------
// fallback fp32 softmax (small-ws path)
// ---------------------------------------------------------------------------
__global__ __launch_bounds__(256) void softmax32_kernel(float* __restrict__ attn) {
  long row = blockIdx.x;
  float* p = attn + row * 4096;
  int t = threadIdx.x;
  __shared__ float red[8];
  float4 v[4];
  float mx = -1e30f;
#pragma unroll
  for (int c = 0; c < 4; ++c) {
    v[c] = *(const float4*)(p + c * 1024 + t * 4);
    mx = fmaxf(mx, fmaxf(fmaxf(v[c].x, v[c].y), fmaxf(v[c].z, v[c].w)));
  }
#pragma unroll
  for (int m = 32; m >= 1; m >>= 1) mx = fmaxf(mx, __shfl_xor(mx, m, 64));
  if ((t & 63) == 0) red[t >> 6] = mx;
  __syncthreads();
  mx = fmaxf(fmaxf(red[0], red[1]), fmaxf(red[2], red[3]));
  float sum = 0.f;
#pragma unroll
  for (int c = 0; c < 4; ++c) {
    v[c].x = __expf(v[c].x - mx);
    v[c].y = __expf(v[c].y - mx);
    v[c].z = __expf(v[c].z - mx);
    v[c].w = __expf(v[c].w - mx);
    sum += v[c].x + v[c].y + v[c].z + v[c].w;
  }
#pragma unroll
  for (int m = 32; m >= 1; m >>= 1) sum += __shfl_xor(sum, m, 64);
  if ((t & 63) == 0) red[4 + (t >> 6)] = sum;
  __syncthreads();
  float inv = 1.f / (red[4] + red[5] + red[6] + red[7]);
#pragma unroll
  for (int c = 0; c < 4; ++c) {
    v[c].x *= inv; v[c].y *= inv; v[c].z *= inv; v[c].w *= inv;
    *(float4*)(p + c * 1024 + t * 4) = v[c];
  }
}

// ---------------------------------------------------------------------------
extern "C" void kernel_launch(void* const* d_in, const int* in_sizes, int n_in,
                              void* d_out, int out_size, void* d_ws, size_t ws_size,
                              hipStream_t stream) {
  const float* x    = (const float*)d_in[0];
  const float* geo  = (const float*)d_in[1];
  const float* Wq   = (const float*)d_in[2];
  const float* bq   = (const float*)d_in[3];
  const float* Wk   = (const float*)d_in[4];
  const float* bk   = (const float*)d_in[5];
  const float* Wv   = (const float*)d_in[6];
  const float* bv   = (const float*)d_in[7];
  const float* Wgp  = (const float*)d_in[8];
  const float* bgp  = (const float*)d_in[9];
  const float* Wgg  = (const float*)d_in[10];
  const float* bgg  = (const float*)d_in[11];

  float* out  = (float*)d_out;                    // [B][C][N]
  float* attn = out + (long)BB * CC * NN;         // [B][N][N]

  char* w = (char*)d_ws;
  size_t used = 0;
  auto alloc = [&](size_t bytes) {
    char* p = w + used;
    used += (bytes + 255) & ~(size_t)255;
    return p;
  };
  bf16*  xt   = (bf16*)alloc((size_t)BB * NN * CC * 2);  // [B][N][C]
  bf16*  geob = (bf16*)alloc((size_t)BB * NN * CC * 2);  // [B][N][C]
  bf16*  qn   = (bf16*)alloc((size_t)BB * NN * CC * 2);  // [B][N][O]
  bf16*  kn   = (bf16*)alloc((size_t)BB * NN * CC * 2);  // [B][N][O]
  bf16*  vb   = (bf16*)alloc((size_t)BB * CC * NN * 2);  // [B][O][N]
  float* ge   = (float*)alloc((size_t)BB * NN * CC * 4); // [B][N][O] fp32
  bf16*  Wall = (bf16*)alloc((size_t)4 * CC * CC * 2);
  bf16*  Wvb  = Wall + 2 * CC * CC;
  // fp16 energy (134MB) + row stats — only if workspace allows
  size_t abf_bytes = (size_t)BB * NN * NN * 2;
  size_t minv_bytes = (size_t)BB * NN * sizeof(float2);
  bool big = (ws_size >= used + abf_bytes + minv_bytes + 512);
  f16* abf = nullptr;
  float2* minv = nullptr;
  if (big) {
    abf = (f16*)alloc(abf_bytes);
    minv = (float2*)alloc(minv_bytes);
  }

  const long NCst = (long)NN * CC;  // 1,048,576
  const long NNst = (long)NN * NN;  // 16,777,216

  // converts + transpose
  cvt_weights_kernel<<<dim3(64, 4), 256, 0, stream>>>(Wq, Wk, Wv, Wgp, Wall);
  cvt_f32_bf16_kernel<<<(BB * NCst) / 1024, 256, 0, stream>>>(geo, geob, BB * NCst);
  transpose_x_kernel<<<dim3(4, 64, BB), 256, 0, stream>>>(x, xt);

  // fused projections: q, ge, k, v
  proj_all_kernel<<<dim3(2, 32, BB * 4), 256, 0, stream>>>(
      xt, geob, Wall, bq, bgp, bk, bv, qn, ge, kn, vb);
  // gate update on qn
  gate_kernel<<<(BB * NN) / 4, 256, 0, stream>>>(qn, ge, Wgg, bgg);

  if (big) {
    // energy = qn . kn^T -> fp16 into abf
    gemm_nt_lds<0, 0, 2, false, true><<<dim3(32, 32, BB), 256, 0, stream>>>(
        qn, kn, nullptr, abf, nullptr, NN, CC, NCst, NCst, NNst, 0);
    // per-row max + 1/sum
    rowstat_kernel<<<BB * NN, 256, 0, stream>>>(abf, minv);
    // fused softmax + PV (+ fp32 attention write, gate epilogue)
    pv_fused_kernel<true><<<dim3(64, 1, BB), 512, 0, stream>>>(
        vb, abf, minv, attn, out, ge);
  } else {
    gemm_nt_lds<0, 0, 0, false, true><<<dim3(32, 32, BB), 256, 0, stream>>>(
        qn, kn, nullptr, attn, nullptr, NN, CC, NCst, NCst, NNst, 0);
    softmax32_kernel<<<BB * NN, 256, 0, stream>>>(attn);
    gemm_nt_lds<0, 1, 0, true, true><<<dim3(32, 2, BB), 256, 0, stream>>>(
        vb, attn, nullptr, out, ge, NN, NN, NCst, NNst, NCst, NCst);
  }
}